// Round 4
// baseline (1803.168 us; speedup 1.0000x reference)
//
#include <hip/hip_runtime.h>
#include <hip/hip_bf16.h>

#define T_  4
#define B_  32
#define C_  512
#define CV_ 2048
#define N_  256
#define NH_ 8
#define DH_ 64
#define DV_ 256

typedef __bf16 bf16_t;
typedef __bf16 bf16x8 __attribute__((ext_vector_type(8)));
typedef float  f32x4  __attribute__((ext_vector_type(4)));
typedef unsigned char u8x8 __attribute__((ext_vector_type(8)));

__device__ __forceinline__ f32x4 mfma16(bf16x8 a, bf16x8 b, f32x4 c) {
  return __builtin_amdgcn_mfma_f32_16x16x32_bf16(a, b, c, 0, 0, 0);
}

// s = round(clip(u,0,8)); rintf = round-half-even, matching jnp.round/np.round
__device__ __forceinline__ float quant_step(float u) {
  return rintf(fminf(fmaxf(u, 0.0f), 8.0f));
}

// uchar8 (spike ints 0..8) -> bf16x8 exact integer values
__device__ __forceinline__ bf16x8 cvt8(u8x8 v) {
  bf16x8 r;
#pragma unroll
  for (int j = 0; j < 8; ++j) r[j] = (bf16_t)(float)(unsigned int)v[j];
  return r;
}

// Storage-dtype sniffer: 1 if tensor at p is f32-stored, 0 if bf16-stored.
// Samples 64 even bf16-slot positions (bytes [0,256); every tensor >= 1 KiB).
__device__ int sniff_f32(const void* p) {
  const unsigned short* u = (const unsigned short*)p;
  int bad = 0, zero = 0;
  for (int j = 0; j < 64; ++j) {
    unsigned short b = u[2 * j];
    if (b == 0 || b == 0x8000) { zero++; continue; }
    int e = (b >> 7) & 0xFF;
    if (e < 96 || e > 141) bad++;
  }
  return (zero >= 32 || bad >= 16) ? 1 : 0;
}

__device__ __forceinline__ float ldparam(const void* p, int f, int i) {
  return f ? ((const float*)p)[i] : (float)((const bf16_t*)p)[i];
}

// Load 8 consecutive weights as bf16 hi (+ lo residual if f32-stored).
__device__ __forceinline__ void load_w8(const void* W, int fw, size_t off,
                                        bf16x8& hi, bf16x8& lo) {
  if (fw) {
    const float* r = (const float*)W + off;
#pragma unroll
    for (int j = 0; j < 8; ++j) {
      float w = r[j];
      __bf16 h = (__bf16)w;
      hi[j] = h;
      lo[j] = (__bf16)(w - (float)h);   // near-exact residual
    }
  } else {
    hi = *(const bf16x8*)((const bf16_t*)W + off);
#pragma unroll
    for (int j = 0; j < 8; ++j) lo[j] = (__bf16)0.0f;
  }
}

// ---------------- Kernel 1: xs = sfa(x) -> xsT [t,b,n,c] bf16 (s/8, exact) --------
__global__ __launch_bounds__(256) void k1_sfa_x(const void* __restrict__ x,
                                                bf16_t* __restrict__ xsT) {
  int fx = sniff_f32(x);
  int g = blockIdx.x * 256 + threadIdx.x;        // B_*C_*N_ threads
  int n = g & (N_ - 1);
  int c = (g >> 8) & (C_ - 1);
  int b = g >> 17;
  float h = 0.0f;
#pragma unroll
  for (int t = 0; t < T_; ++t) {
    size_t idx = ((size_t)(t * B_ + b) * C_ + c) * N_ + n;
    float xv = fx ? ((const float*)x)[idx] : (float)((const bf16_t*)x)[idx];
    float u  = __fadd_rn(h, xv);                 // same op/order as reference scan
    float s  = quant_step(u);
    h = __fsub_rn(u, s);                         // exact
    xsT[((size_t)(t * B_ + b) * N_ + n) * C_ + c] = (bf16_t)(s * 0.125f);  // exact
  }
}

// ---------------- Kernel 2: q|k|v = sfa(conv_bn(xs, W)), spikes stored as u8 ------
__global__ __launch_bounds__(256) void k2_qkv(
    const bf16_t* __restrict__ xsT,
    const void* __restrict__ wq, const void* __restrict__ wk, const void* __restrict__ wv,
    const void* __restrict__ q_scale, const void* __restrict__ q_bias,
    const void* __restrict__ k_scale, const void* __restrict__ k_bias,
    const void* __restrict__ v_scale, const void* __restrict__ v_bias,
    unsigned char* __restrict__ q_s8, unsigned char* __restrict__ k_s8,
    unsigned char* __restrict__ v_s8) {
  int ct = blockIdx.x;                 // 0..95: 16 q-tiles, 16 k-tiles, 64 v-tiles
  int b  = blockIdx.y;
  int tid = threadIdx.x;
  int w = tid >> 6, lane = tid & 63, quad = lane >> 4, l16 = lane & 15;

  const void *W, *scp, *bip;
  int mode, co0;
  if (ct < 16)      { mode = 0; co0 = ct * 32;        W = wq; scp = q_scale; bip = q_bias; }
  else if (ct < 32) { mode = 1; co0 = (ct - 16) * 32; W = wk; scp = k_scale; bip = k_bias; }
  else              { mode = 2; co0 = (ct - 32) * 32; W = wv; scp = v_scale; bip = v_bias; }

  int fw = sniff_f32(W), fs = sniff_f32(scp), fb = sniff_f32(bip);

  float sc[2][4], bi[2][4];
#pragma unroll
  for (int mt = 0; mt < 2; ++mt)
#pragma unroll
    for (int r = 0; r < 4; ++r) {
      int c = co0 + mt * 16 + quad * 4 + r;
      sc[mt][r] = ldparam(scp, fs, c);
      bi[mt][r] = ldparam(bip, fb, c);
    }

  float hst[2][4][4];
#pragma unroll
  for (int mt = 0; mt < 2; ++mt)
#pragma unroll
    for (int nt = 0; nt < 4; ++nt)
#pragma unroll
      for (int r = 0; r < 4; ++r) hst[mt][nt][r] = 0.0f;

  int n0 = w * 64;
  for (int t = 0; t < T_; ++t) {
    f32x4 acc[2][4];
#pragma unroll
    for (int mt = 0; mt < 2; ++mt)
#pragma unroll
      for (int nt = 0; nt < 4; ++nt) acc[mt][nt] = (f32x4){0.f, 0.f, 0.f, 0.f};

    const bf16_t* xrow = xsT + (size_t)(t * B_ + b) * N_ * C_;
    for (int kc = 0; kc < 16; ++kc) {            // K = 512, chunks of 32
      int koff = kc * 32 + quad * 8;
      bf16x8 a0h, a0l, a1h, a1l;
      load_w8(W, fw, (size_t)(co0 + l16) * C_ + koff, a0h, a0l);
      load_w8(W, fw, (size_t)(co0 + 16 + l16) * C_ + koff, a1h, a1l);
      bf16x8 bfr[4];
#pragma unroll
      for (int nt = 0; nt < 4; ++nt)
        bfr[nt] = *(const bf16x8*)(xrow + (size_t)(n0 + nt * 16 + l16) * C_ + koff);
#pragma unroll
      for (int nt = 0; nt < 4; ++nt) {
        acc[0][nt] = mfma16(a0h, bfr[nt], acc[0][nt]);
        acc[1][nt] = mfma16(a1h, bfr[nt], acc[1][nt]);
      }
      if (fw) {
#pragma unroll
        for (int nt = 0; nt < 4; ++nt) {
          acc[0][nt] = mfma16(a0l, bfr[nt], acc[0][nt]);
          acc[1][nt] = mfma16(a1l, bfr[nt], acc[1][nt]);
        }
      }
    }
    // epilogue: affine (no FMA contraction) + sfa scan + spike-int write
#pragma unroll
    for (int mt = 0; mt < 2; ++mt)
#pragma unroll
      for (int nt = 0; nt < 4; ++nt)
#pragma unroll
        for (int r = 0; r < 4; ++r) {
          float y = __fmul_rn(acc[mt][nt][r], sc[mt][r]);
          y = __fadd_rn(y, bi[mt][r]);
          float u = __fadd_rn(hst[mt][nt][r], y);
          float s = quant_step(u);
          hst[mt][nt][r] = __fsub_rn(u, s);
          unsigned char sp = (unsigned char)s;
          int co = co0 + mt * 16 + quad * 4 + r;
          int n  = n0 + nt * 16 + l16;
          if (mode == 0)      q_s8[((size_t)(t * B_ + b) * N_ + n) * C_ + co] = sp;
          else if (mode == 1) k_s8[((size_t)(t * B_ + b) * C_ + co) * N_ + n] = sp;
          else                v_s8[((size_t)(t * B_ + b) * CV_ + co) * N_ + n] = sp;
        }
  }
}

// ---------------- Kernel 3: attention (q·(k^T v)) + sfa, exact integer math -------
__global__ __launch_bounds__(256) void k3_attn(
    const unsigned char* __restrict__ q_s8, const unsigned char* __restrict__ k_s8,
    const unsigned char* __restrict__ v_s8, unsigned char* __restrict__ a_s8) {
  __shared__ float kvbuf[64 * 68];               // 17 KB, [d][e] padded
  int et = blockIdx.x, hh = blockIdx.y, b = blockIdx.z;
  int tid = threadIdx.x;
  int w = tid >> 6, lane = tid & 63, quad = lane >> 4, l16 = lane & 15;
  int e0 = et * 64;

  f32x4 Aacc[4][4];                              // holds 32h + P, exact
#pragma unroll
  for (int mt = 0; mt < 4; ++mt)
#pragma unroll
    for (int nt = 0; nt < 4; ++nt) Aacc[mt][nt] = (f32x4){0.f, 0.f, 0.f, 0.f};

  for (int t = 0; t < T_; ++t) {
    size_t tb = (size_t)(t * B_ + b);
    // Phase A: kv[d][e] = sum_n s_k[d,n] s_v[e,n]  (exact ints in f32)
    f32x4 kva[4];
#pragma unroll
    for (int et2 = 0; et2 < 4; ++et2) kva[et2] = (f32x4){0.f, 0.f, 0.f, 0.f};
    const unsigned char* krow  = k_s8 + ((size_t)tb * C_ + hh * DH_ + w * 16 + l16) * N_;
    const unsigned char* vbase = v_s8 + ((size_t)tb * CV_ + hh * DV_ + e0) * N_;
    for (int kc = 0; kc < 8; ++kc) {             // K = N = 256
      int koff = kc * 32 + quad * 8;
      bf16x8 a = cvt8(*(const u8x8*)(krow + koff));
#pragma unroll
      for (int et2 = 0; et2 < 4; ++et2) {
        bf16x8 bb = cvt8(*(const u8x8*)(vbase + (size_t)(et2 * 16 + l16) * N_ + koff));
        kva[et2] = mfma16(a, bb, kva[et2]);
      }
    }
    __syncthreads();                              // prior phase-B LDS reads done
#pragma unroll
    for (int et2 = 0; et2 < 4; ++et2)
#pragma unroll
      for (int r = 0; r < 4; ++r)
        kvbuf[(w * 16 + quad * 4 + r) * 68 + et2 * 16 + l16] = kva[et2][r];
    __syncthreads();

    // Phase B: P[e][n] += sum_d (kv[d][e]/64) * s_q[n,d], kv/64 split hi+lo (exact)
    const unsigned char* qrow = q_s8 + ((size_t)tb * N_ + w * 64) * C_ + hh * DH_;
    for (int kc2 = 0; kc2 < 2; ++kc2) {          // K = d = 64
      int kbase = kc2 * 32 + quad * 8;
      bf16x8 bq[4];
#pragma unroll
      for (int nt = 0; nt < 4; ++nt)
        bq[nt] = cvt8(*(const u8x8*)(qrow + (size_t)(nt * 16 + l16) * C_ + kbase));
#pragma unroll
      for (int mt = 0; mt < 4; ++mt) {
        bf16x8 ahi, alo;
#pragma unroll
        for (int j = 0; j < 8; ++j) {
          float v = kvbuf[(kbase + j) * 68 + mt * 16 + l16] * 0.015625f;  // /64 exact
          __bf16 hi = (__bf16)v;
          ahi[j] = hi;
          alo[j] = (__bf16)(v - (float)hi);      // exact residual
        }
#pragma unroll
        for (int nt = 0; nt < 4; ++nt) {
          Aacc[mt][nt] = mfma16(ahi, bq[nt], Aacc[mt][nt]);
          Aacc[mt][nt] = mfma16(alo, bq[nt], Aacc[mt][nt]);
        }
      }
    }
    // epilogue: u = Aacc/32 (exact); spike; state Aacc -= 32*s
#pragma unroll
    for (int mt = 0; mt < 4; ++mt)
#pragma unroll
      for (int nt = 0; nt < 4; ++nt)
#pragma unroll
        for (int r = 0; r < 4; ++r) {
          float u = Aacc[mt][nt][r] * 0.03125f;
          float s = quant_step(u);
          int cv = hh * DV_ + e0 + mt * 16 + quad * 4 + r;
          int n  = w * 64 + nt * 16 + l16;
          a_s8[(tb * N_ + n) * CV_ + cv] = (unsigned char)s;
          Aacc[mt][nt][r] = __fsub_rn(Aacc[mt][nt][r], 32.0f * s);
        }
  }
}

// ---------------- Kernel 4: out = conv_bn(attn spike ints / 8, wp), f32 out -------
__global__ __launch_bounds__(256) void k4_pconv(
    const unsigned char* __restrict__ a_s8, const void* __restrict__ wp,
    const void* __restrict__ p_scale, const void* __restrict__ p_bias,
    float* __restrict__ out) {
  int ctile = blockIdx.x;              // 16 -> co0
  int tb    = blockIdx.y;              // 128 = t*B_+b
  int tid = threadIdx.x;
  int w = tid >> 6, lane = tid & 63, quad = lane >> 4, l16 = lane & 15;
  int co0 = ctile * 32, n0 = w * 64;

  int fw = sniff_f32(wp), fs = sniff_f32(p_scale), fb = sniff_f32(p_bias);

  float sc[2][4], bi[2][4];            // sc pre-folds the /8 (exact pow2)
#pragma unroll
  for (int mt = 0; mt < 2; ++mt)
#pragma unroll
    for (int r = 0; r < 4; ++r) {
      int c = co0 + mt * 16 + quad * 4 + r;
      sc[mt][r] = ldparam(p_scale, fs, c) * 0.125f;
      bi[mt][r] = ldparam(p_bias, fb, c);
    }

  f32x4 acc[2][4];
#pragma unroll
  for (int mt = 0; mt < 2; ++mt)
#pragma unroll
    for (int nt = 0; nt < 4; ++nt) acc[mt][nt] = (f32x4){0.f, 0.f, 0.f, 0.f};

  const unsigned char* arow = a_s8 + ((size_t)tb * N_ + n0) * CV_;
  for (int kc = 0; kc < 64; ++kc) {    // K = 2048
    int koff = kc * 32 + quad * 8;
    bf16x8 a0h, a0l, a1h, a1l;
    load_w8(wp, fw, (size_t)(co0 + l16) * CV_ + koff, a0h, a0l);
    load_w8(wp, fw, (size_t)(co0 + 16 + l16) * CV_ + koff, a1h, a1l);
    bf16x8 bfr[4];
#pragma unroll
    for (int nt = 0; nt < 4; ++nt)
      bfr[nt] = cvt8(*(const u8x8*)(arow + (size_t)(nt * 16 + l16) * CV_ + koff));
#pragma unroll
    for (int nt = 0; nt < 4; ++nt) {
      acc[0][nt] = mfma16(a0h, bfr[nt], acc[0][nt]);
      acc[1][nt] = mfma16(a1h, bfr[nt], acc[1][nt]);
    }
    if (fw) {
#pragma unroll
      for (int nt = 0; nt < 4; ++nt) {
        acc[0][nt] = mfma16(a0l, bfr[nt], acc[0][nt]);
        acc[1][nt] = mfma16(a1l, bfr[nt], acc[1][nt]);
      }
    }
  }
#pragma unroll
  for (int mt = 0; mt < 2; ++mt)
#pragma unroll
    for (int nt = 0; nt < 4; ++nt)
#pragma unroll
      for (int r = 0; r < 4; ++r) {
        float y = __fmul_rn(acc[mt][nt][r], sc[mt][r]);
        y = __fadd_rn(y, bi[mt][r]);
        int co = co0 + mt * 16 + quad * 4 + r;
        int n  = n0 + nt * 16 + l16;
        out[((size_t)tb * C_ + co) * N_ + n] = y;   // f32 store (reference out dtype)
      }
}

extern "C" void kernel_launch(void* const* d_in, const int* in_sizes, int n_in,
                              void* d_out, int out_size, void* d_ws, size_t ws_size,
                              hipStream_t stream) {
  const void* x       = d_in[0];
  const void* wq      = d_in[1];
  const void* wk      = d_in[2];
  const void* wv      = d_in[3];
  const void* wp      = d_in[4];
  const void* q_scale = d_in[5];
  const void* q_bias  = d_in[6];
  const void* k_scale = d_in[7];
  const void* k_bias  = d_in[8];
  const void* v_scale = d_in[9];
  const void* v_bias  = d_in[10];
  const void* p_scale = d_in[11];
  const void* p_bias  = d_in[12];

  // workspace layout (160 MiB):
  //   [0,64M)   a_s8 [T,B,N,CV] u8   (xsT bf16 [T,B,N,C] 32 MiB aliases [0,32M);
  //                                   xsT dead after K2, a_s8 written in K3)
  //   [64,80M)  q_s8 [T,B,N,C] u8
  //   [80,96M)  k_s8 [T,B,C,N] u8
  //   [96,160M) v_s8 [T,B,CV,N] u8
  const size_t MB = 1024 * 1024;
  if (ws_size < 160 * MB) return;
  char* ws = (char*)d_ws;
  unsigned char* a_s8 = (unsigned char*)(ws);
  bf16_t*        xsT  = (bf16_t*)(ws);
  unsigned char* q_s8 = (unsigned char*)(ws + 64 * MB);
  unsigned char* k_s8 = (unsigned char*)(ws + 80 * MB);
  unsigned char* v_s8 = (unsigned char*)(ws + 96 * MB);

  k1_sfa_x<<<(B_ * C_ * N_) / 256, 256, 0, stream>>>(x, xsT);
  k2_qkv<<<dim3(96, B_), 256, 0, stream>>>(xsT, wq, wk, wv,
                                           q_scale, q_bias, k_scale, k_bias,
                                           v_scale, v_bias, q_s8, k_s8, v_s8);
  k3_attn<<<dim3(4, NH_, B_), 256, 0, stream>>>(q_s8, k_s8, v_s8, a_s8);
  k4_pconv<<<dim3(16, T_ * B_), 256, 0, stream>>>(a_s8, wp, p_scale, p_bias,
                                                  (float*)d_out);
}

// Round 5
// 835.873 us; speedup vs baseline: 2.1572x; 2.1572x over previous
//
#include <hip/hip_runtime.h>
#include <hip/hip_bf16.h>

#define T_  4
#define B_  32
#define C_  512
#define CV_ 2048
#define N_  256
#define NH_ 8
#define DH_ 64
#define DV_ 256

typedef __bf16 bf16_t;
typedef __bf16 bf16x8 __attribute__((ext_vector_type(8)));
typedef float  f32x4  __attribute__((ext_vector_type(4)));
typedef unsigned char u8x8 __attribute__((ext_vector_type(8)));

#if defined(__has_builtin)
# if __has_builtin(__builtin_amdgcn_global_load_lds)
#  define USE_GLL 1
# endif
#endif

__device__ __forceinline__ f32x4 mfma16(bf16x8 a, bf16x8 b, f32x4 c) {
  return __builtin_amdgcn_mfma_f32_16x16x32_bf16(a, b, c, 0, 0, 0);
}

// s = round(clip(u,0,8)); rintf = round-half-even, matching jnp.round/np.round
__device__ __forceinline__ float quant_step(float u) {
  return rintf(fminf(fmaxf(u, 0.0f), 8.0f));
}

// uchar8 (spike ints 0..8) -> bf16x8 exact integer values
__device__ __forceinline__ bf16x8 cvt8(u8x8 v) {
  bf16x8 r;
#pragma unroll
  for (int j = 0; j < 8; ++j) r[j] = (bf16_t)(float)(unsigned int)v[j];
  return r;
}

// Async 16B/lane global->LDS stage. lbase must be wave-uniform; HW dest =
// lbase + lane*16 (m104/m108). Fallback: VGPR round-trip.
__device__ __forceinline__ void stage16(const void* g, void* lbase, int lane) {
#ifdef USE_GLL
  __builtin_amdgcn_global_load_lds(
      (const __attribute__((address_space(1))) void*)g,
      (__attribute__((address_space(3))) void*)lbase, 16, 0, 0);
#else
  *(uint4*)((char*)lbase + lane * 16) = *(const uint4*)g;
#endif
}

// ---------------- Kernel 0: split f32 weights into bf16 hi + lo ----------------
__global__ __launch_bounds__(256) void k0_split(const float* __restrict__ src,
                                                bf16_t* __restrict__ hi,
                                                bf16_t* __restrict__ lo, int n8) {
  int i = blockIdx.x * 256 + threadIdx.x;
  if (i >= n8) return;
  const float* s = src + (size_t)i * 8;
  bf16x8 h, l;
#pragma unroll
  for (int j = 0; j < 8; ++j) {
    float w = s[j];
    __bf16 hh = (__bf16)w;
    h[j] = hh;
    l[j] = (__bf16)(w - (float)hh);   // near-exact residual
  }
  *(bf16x8*)(hi + (size_t)i * 8) = h;
  *(bf16x8*)(lo + (size_t)i * 8) = l;
}

// ---------------- Kernel 1: xs = sfa(x) -> xsT [t,b,n,c] bf16 (s/8) ----------------
// LDS tile transpose: coalesced f32 reads (n-contig) and bf16 writes (c-contig).
__global__ __launch_bounds__(256) void k1_sfa_x(const float* __restrict__ x,
                                                bf16_t* __restrict__ xsT) {
  __shared__ bf16_t tile[64 * 72];               // [n][c], pad 72
  int bt = blockIdx.x;                            // 0..31: c-tile = bt>>2, n-tile = bt&3
  int b  = blockIdx.y;
  int tid = threadIdx.x;
  int c0 = (bt >> 2) * 64, n0 = (bt & 3) * 64;
  int cl = tid >> 2, nc = (tid & 3) * 16;        // reader role: c-row, 16-n chunk
  int nl = tid >> 2, cj = (tid & 3) * 16;        // writer role: n-row, 16-c chunk

  float h[16];
#pragma unroll
  for (int j = 0; j < 16; ++j) h[j] = 0.0f;

  for (int t = 0; t < T_; ++t) {
    const float* xp = x + ((size_t)(t * B_ + b) * C_ + c0 + cl) * N_ + n0 + nc;
    f32x4 xv[4];
#pragma unroll
    for (int j = 0; j < 4; ++j) xv[j] = *(const f32x4*)(xp + j * 4);
    if (t) __syncthreads();                      // prior reads done before overwrite
#pragma unroll
    for (int j = 0; j < 16; ++j) {
      float u = __fadd_rn(h[j], xv[j >> 2][j & 3]);  // reference scan op order
      float s = quant_step(u);
      h[j] = __fsub_rn(u, s);                    // exact
      tile[(nc + j) * 72 + cl] = (bf16_t)(s * 0.125f);  // exact
    }
    __syncthreads();
    bf16x8 o0 = *(const bf16x8*)&tile[nl * 72 + cj];
    bf16x8 o1 = *(const bf16x8*)&tile[nl * 72 + cj + 8];
    bf16_t* op = xsT + ((size_t)(t * B_ + b) * N_ + n0 + nl) * C_ + c0 + cj;
    *(bf16x8*)op = o0;
    *(bf16x8*)(op + 8) = o1;
  }
}

// ---------------- Kernel 2: q|k|v = sfa(conv_bn(xs, W)), LDS-staged MFMA ----------
// Block: 64 co x 256 n, one b; t-loop inside (scan state in regs). BK=64.
// LDS layouts use 16B-granule XOR swizzle (granule m holds data kblk = m ^ (row&7))
// so global_load_lds stays lane-contiguous AND ds_read_b128 is ~conflict-free.
__global__ __launch_bounds__(256) void k2_qkv(
    const bf16_t* __restrict__ xsT,
    const bf16_t* __restrict__ w_hi, const bf16_t* __restrict__ w_lo,
    const float* __restrict__ q_scale, const float* __restrict__ q_bias,
    const float* __restrict__ k_scale, const float* __restrict__ k_bias,
    const float* __restrict__ v_scale, const float* __restrict__ v_bias,
    unsigned char* __restrict__ q_s8, unsigned char* __restrict__ k_s8,
    unsigned char* __restrict__ v_s8) {
  __shared__ __align__(16) bf16_t xs_l[256 * 64];   // 32 KB
  __shared__ __align__(16) bf16_t whi_l[64 * 64];   //  8 KB
  __shared__ __align__(16) bf16_t wlo_l[64 * 64];   //  8 KB

  int ct = blockIdx.x;                 // 0..47: 8 q, 8 k, 32 v co-tiles
  int b  = blockIdx.y;
  int tid = threadIdx.x;
  int w = tid >> 6, lane = tid & 63, quad = lane >> 4, l16 = lane & 15;
  int nl = lane >> 3, m8 = lane & 7;   // staging roles

  int mode, co_out;
  const float *scp, *bip;
  if (ct < 8)       { mode = 0; co_out = ct * 64;        scp = q_scale; bip = q_bias; }
  else if (ct < 16) { mode = 1; co_out = (ct - 8) * 64;  scp = k_scale; bip = k_bias; }
  else              { mode = 2; co_out = (ct - 16) * 64; scp = v_scale; bip = v_bias; }

  const bf16_t* wrow = w_hi + (size_t)ct * 64 * C_;  // combined rows: ct*64
  const bf16_t* lrow = w_lo + (size_t)ct * 64 * C_;

  float hst[4][4][4];
#pragma unroll
  for (int mt = 0; mt < 4; ++mt)
#pragma unroll
    for (int nt = 0; nt < 4; ++nt)
#pragma unroll
      for (int r = 0; r < 4; ++r) hst[mt][nt][r] = 0.0f;

  for (int t = 0; t < T_; ++t) {
    const bf16_t* xrow = xsT + (size_t)(t * B_ + b) * N_ * C_;
    f32x4 acc[4][4];
#pragma unroll
    for (int mt = 0; mt < 4; ++mt)
#pragma unroll
      for (int nt = 0; nt < 4; ++nt) acc[mt][nt] = (f32x4){0.f, 0.f, 0.f, 0.f};

    for (int kc = 0; kc < 8; ++kc) {             // K = 512, BK = 64
      int c0 = kc * 64;
      __syncthreads();                            // prior compute done before overwrite
      // stage xs chunk [256n x 64c]: wave w rows [w*64, w*64+64), 8 rows/instr
#pragma unroll
      for (int j = 0; j < 8; ++j) {
        int r0 = w * 64 + j * 8;
        int row = r0 + nl;
        int col = c0 + ((m8 ^ nl) << 3);
        stage16(xrow + (size_t)row * C_ + col, (char*)xs_l + r0 * 128, lane);
      }
      // stage w_hi/w_lo chunk [64co x 64c]: wave w rows w*16 + j*8
#pragma unroll
      for (int j = 0; j < 2; ++j) {
        int r0 = w * 16 + j * 8;
        int row = r0 + nl;
        int col = c0 + ((m8 ^ nl) << 3);
        stage16(wrow + (size_t)row * C_ + col, (char*)whi_l + r0 * 128, lane);
        stage16(lrow + (size_t)row * C_ + col, (char*)wlo_l + r0 * 128, lane);
      }
      __syncthreads();                            // drains vmcnt (global_load_lds)
      // compute: 64 MFMAs / wave per chunk
#pragma unroll
      for (int ks = 0; ks < 2; ++ks) {
        int kb = ks * 4 + quad;
        bf16x8 bx[4];
#pragma unroll
        for (int nt = 0; nt < 4; ++nt) {
          int row = w * 64 + nt * 16 + l16;
          int blk = row * 8 + (kb ^ (row & 7));
          bx[nt] = *(const bf16x8*)((char*)xs_l + blk * 16);
        }
#pragma unroll
        for (int mt = 0; mt < 4; ++mt) {
          int row = mt * 16 + l16;
          int blk = row * 8 + (kb ^ (row & 7));
          bf16x8 ah = *(const bf16x8*)((char*)whi_l + blk * 16);
          bf16x8 al = *(const bf16x8*)((char*)wlo_l + blk * 16);
#pragma unroll
          for (int nt = 0; nt < 4; ++nt) {
            acc[mt][nt] = mfma16(ah, bx[nt], acc[mt][nt]);
            acc[mt][nt] = mfma16(al, bx[nt], acc[mt][nt]);
          }
        }
      }
    }
    // epilogue: affine (no FMA contraction) + sfa scan + spike-int store
#pragma unroll
    for (int mt = 0; mt < 4; ++mt)
#pragma unroll
      for (int r = 0; r < 4; ++r) {
        int c = co_out + mt * 16 + quad * 4 + r;
        float scv = scp[c], biv = bip[c];
#pragma unroll
        for (int nt = 0; nt < 4; ++nt) {
          float y = __fmul_rn(acc[mt][nt][r], scv);
          y = __fadd_rn(y, biv);
          float u = __fadd_rn(hst[mt][nt][r], y);
          float s = quant_step(u);
          hst[mt][nt][r] = __fsub_rn(u, s);
          unsigned char sp = (unsigned char)s;
          int n = w * 64 + nt * 16 + l16;
          if (mode == 0)      q_s8[((size_t)(t * B_ + b) * N_ + n) * C_ + c] = sp;
          else if (mode == 1) k_s8[((size_t)(t * B_ + b) * C_ + c) * N_ + n] = sp;
          else                v_s8[((size_t)(t * B_ + b) * CV_ + c) * N_ + n] = sp;
        }
      }
  }
}

// ---------------- Kernel 3: attention (q·(k^T v)) + sfa, exact (unchanged R4) -----
__global__ __launch_bounds__(256) void k3_attn(
    const unsigned char* __restrict__ q_s8, const unsigned char* __restrict__ k_s8,
    const unsigned char* __restrict__ v_s8, unsigned char* __restrict__ a_s8) {
  __shared__ float kvbuf[64 * 68];
  int et = blockIdx.x, hh = blockIdx.y, b = blockIdx.z;
  int tid = threadIdx.x;
  int w = tid >> 6, lane = tid & 63, quad = lane >> 4, l16 = lane & 15;
  int e0 = et * 64;

  f32x4 Aacc[4][4];
#pragma unroll
  for (int mt = 0; mt < 4; ++mt)
#pragma unroll
    for (int nt = 0; nt < 4; ++nt) Aacc[mt][nt] = (f32x4){0.f, 0.f, 0.f, 0.f};

  for (int t = 0; t < T_; ++t) {
    size_t tb = (size_t)(t * B_ + b);
    f32x4 kva[4];
#pragma unroll
    for (int et2 = 0; et2 < 4; ++et2) kva[et2] = (f32x4){0.f, 0.f, 0.f, 0.f};
    const unsigned char* krow  = k_s8 + ((size_t)tb * C_ + hh * DH_ + w * 16 + l16) * N_;
    const unsigned char* vbase = v_s8 + ((size_t)tb * CV_ + hh * DV_ + e0) * N_;
    for (int kc = 0; kc < 8; ++kc) {
      int koff = kc * 32 + quad * 8;
      bf16x8 a = cvt8(*(const u8x8*)(krow + koff));
#pragma unroll
      for (int et2 = 0; et2 < 4; ++et2) {
        bf16x8 bb = cvt8(*(const u8x8*)(vbase + (size_t)(et2 * 16 + l16) * N_ + koff));
        kva[et2] = mfma16(a, bb, kva[et2]);
      }
    }
    __syncthreads();
#pragma unroll
    for (int et2 = 0; et2 < 4; ++et2)
#pragma unroll
      for (int r = 0; r < 4; ++r)
        kvbuf[(w * 16 + quad * 4 + r) * 68 + et2 * 16 + l16] = kva[et2][r];
    __syncthreads();

    const unsigned char* qrow = q_s8 + ((size_t)tb * N_ + w * 64) * C_ + hh * DH_;
    for (int kc2 = 0; kc2 < 2; ++kc2) {
      int kbase = kc2 * 32 + quad * 8;
      bf16x8 bq[4];
#pragma unroll
      for (int nt = 0; nt < 4; ++nt)
        bq[nt] = cvt8(*(const u8x8*)(qrow + (size_t)(nt * 16 + l16) * C_ + kbase));
#pragma unroll
      for (int mt = 0; mt < 4; ++mt) {
        bf16x8 ahi, alo;
#pragma unroll
        for (int j = 0; j < 8; ++j) {
          float v = kvbuf[(kbase + j) * 68 + mt * 16 + l16] * 0.015625f;
          __bf16 hi = (__bf16)v;
          ahi[j] = hi;
          alo[j] = (__bf16)(v - (float)hi);
        }
#pragma unroll
        for (int nt = 0; nt < 4; ++nt) {
          Aacc[mt][nt] = mfma16(ahi, bq[nt], Aacc[mt][nt]);
          Aacc[mt][nt] = mfma16(alo, bq[nt], Aacc[mt][nt]);
        }
      }
    }
#pragma unroll
    for (int mt = 0; mt < 4; ++mt)
#pragma unroll
      for (int nt = 0; nt < 4; ++nt)
#pragma unroll
        for (int r = 0; r < 4; ++r) {
          float u = Aacc[mt][nt][r] * 0.03125f;
          float s = quant_step(u);
          int cv = hh * DV_ + e0 + mt * 16 + quad * 4 + r;
          int n  = w * 64 + nt * 16 + l16;
          a_s8[(tb * N_ + n) * CV_ + cv] = (unsigned char)s;
          Aacc[mt][nt][r] = __fsub_rn(Aacc[mt][nt][r], 32.0f * s);
        }
  }
}

// ---------------- Kernel 4: out = conv_bn(attn spikes/8, wp), LDS-staged ----------
__global__ __launch_bounds__(256) void k4_pconv(
    const unsigned char* __restrict__ a_s8,
    const bf16_t* __restrict__ wp_hi, const bf16_t* __restrict__ wp_lo,
    const float* __restrict__ p_scale, const float* __restrict__ p_bias,
    float* __restrict__ out) {
  __shared__ __align__(16) unsigned char as_l[256 * 64];  // 16 KB
  __shared__ __align__(16) bf16_t whi_l[64 * 64];         //  8 KB
  __shared__ __align__(16) bf16_t wlo_l[64 * 64];         //  8 KB

  int ct = blockIdx.x;                 // 0..7 co-tile
  int tb = blockIdx.y;                 // 0..127 = t*B_+b
  int tid = threadIdx.x;
  int w = tid >> 6, lane = tid & 63, quad = lane >> 4, l16 = lane & 15;
  int nl = lane >> 3, m8 = lane & 7;
  int nl4 = lane >> 2, m4 = lane & 3;
  int co0 = ct * 64;

  const unsigned char* arow = a_s8 + (size_t)tb * N_ * CV_;
  const bf16_t* wrow = wp_hi + (size_t)co0 * CV_;
  const bf16_t* lrow = wp_lo + (size_t)co0 * CV_;

  f32x4 acc[4][4];
#pragma unroll
  for (int mt = 0; mt < 4; ++mt)
#pragma unroll
    for (int nt = 0; nt < 4; ++nt) acc[mt][nt] = (f32x4){0.f, 0.f, 0.f, 0.f};

  for (int kc = 0; kc < 32; ++kc) {    // K = 2048, BK = 64
    int c0 = kc * 64;
    __syncthreads();
    // stage a chunk [256n x 64cv] u8 (row = 64B = 4 granules): 16 rows/instr
#pragma unroll
    for (int j = 0; j < 4; ++j) {
      int r0 = w * 64 + j * 16;
      int row = r0 + nl4;
      int col = c0 + ((m4 ^ (nl4 & 3)) << 4);
      stage16(arow + (size_t)row * CV_ + col, (char*)as_l + r0 * 64, lane);
    }
    // stage wp_hi/wp_lo chunk [64co x 64c] bf16
#pragma unroll
    for (int j = 0; j < 2; ++j) {
      int r0 = w * 16 + j * 8;
      int row = r0 + nl;
      int col = c0 + ((m8 ^ nl) << 3);
      stage16(wrow + (size_t)row * CV_ + col, (char*)whi_l + r0 * 128, lane);
      stage16(lrow + (size_t)row * CV_ + col, (char*)wlo_l + r0 * 128, lane);
    }
    __syncthreads();
#pragma unroll
    for (int ks = 0; ks < 2; ++ks) {
      int kb = ks * 4 + quad;          // 8-elem granule index 0..7
      bf16x8 ba[4];
#pragma unroll
      for (int nt = 0; nt < 4; ++nt) {
        int row = w * 64 + nt * 16 + l16;
        int blk16 = (kb >> 1) ^ (row & 3);
        const char* p = (const char*)as_l + row * 64 + blk16 * 16 + (kb & 1) * 8;
        ba[nt] = cvt8(*(const u8x8*)p);
      }
#pragma unroll
      for (int mt = 0; mt < 4; ++mt) {
        int row = mt * 16 + l16;
        int blk = row * 8 + (kb ^ (row & 7));
        bf16x8 ah = *(const bf16x8*)((char*)whi_l + blk * 16);
        bf16x8 al = *(const bf16x8*)((char*)wlo_l + blk * 16);
#pragma unroll
        for (int nt = 0; nt < 4; ++nt) {
          acc[mt][nt] = mfma16(ah, ba[nt], acc[mt][nt]);
          acc[mt][nt] = mfma16(al, ba[nt], acc[mt][nt]);
        }
      }
    }
  }
#pragma unroll
  for (int mt = 0; mt < 4; ++mt)
#pragma unroll
    for (int r = 0; r < 4; ++r) {
      int c = co0 + mt * 16 + quad * 4 + r;
      float scv = __fmul_rn(p_scale[c], 0.125f);  // exact pow2 fold
      float biv = p_bias[c];
#pragma unroll
      for (int nt = 0; nt < 4; ++nt) {
        float y = __fmul_rn(acc[mt][nt][r], scv);
        y = __fadd_rn(y, biv);
        int n = w * 64 + nt * 16 + l16;
        out[((size_t)tb * C_ + c) * N_ + n] = y;
      }
    }
}

extern "C" void kernel_launch(void* const* d_in, const int* in_sizes, int n_in,
                              void* d_out, int out_size, void* d_ws, size_t ws_size,
                              hipStream_t stream) {
  const float* x       = (const float*)d_in[0];
  const float* wq      = (const float*)d_in[1];
  const float* wk      = (const float*)d_in[2];
  const float* wv      = (const float*)d_in[3];
  const float* wp      = (const float*)d_in[4];
  const float* q_scale = (const float*)d_in[5];
  const float* q_bias  = (const float*)d_in[6];
  const float* k_scale = (const float*)d_in[7];
  const float* k_bias  = (const float*)d_in[8];
  const float* v_scale = (const float*)d_in[9];
  const float* v_bias  = (const float*)d_in[10];
  const float* p_scale = (const float*)d_in[11];
  const float* p_bias  = (const float*)d_in[12];

  // workspace (160 MiB), time-multiplexed:
  //  [0,32M)   xsT bf16 [T,B,N,C]      (K1 out, K2 in; dead after K2)
  //  [32,38M)  w_qkv hi|lo bf16 [3072x512] (k0 out, K2 in; dead after K2)
  //  [0,64M)   a_s8 [T,B,N,CV]         (K3 out, K4 in) -- clobbers the two above
  //  [64,80M)  q_s8 [T,B,N,C]          (K2 out, K3 in; dead after K3)
  //  [64,66M)+[66,68M) wp hi|lo        (k0p out after K3, K4 in)
  //  [80,96M)  k_s8 [T,B,C,N]
  //  [96,160M) v_s8 [T,B,CV,N]
  const size_t MB = 1024 * 1024;
  if (ws_size < 160 * MB) return;
  char* ws = (char*)d_ws;
  bf16_t*        xsT    = (bf16_t*)(ws);
  unsigned char* a_s8   = (unsigned char*)(ws);
  bf16_t*        wqkv_h = (bf16_t*)(ws + 32 * MB);
  bf16_t*        wqkv_l = (bf16_t*)(ws + 35 * MB);
  unsigned char* q_s8   = (unsigned char*)(ws + 64 * MB);
  bf16_t*        wp_h   = (bf16_t*)(ws + 64 * MB);
  bf16_t*        wp_l   = (bf16_t*)(ws + 66 * MB);
  unsigned char* k_s8   = (unsigned char*)(ws + 80 * MB);
  unsigned char* v_s8   = (unsigned char*)(ws + 96 * MB);

  // weight splits: combined rows [wq | wk | wv] of length C_
  k0_split<<<128, 256, 0, stream>>>(wq, wqkv_h, wqkv_l, 32768);
  k0_split<<<128, 256, 0, stream>>>(wk, wqkv_h + 262144, wqkv_l + 262144, 32768);
  k0_split<<<512, 256, 0, stream>>>(wv, wqkv_h + 524288, wqkv_l + 524288, 131072);

  k1_sfa_x<<<dim3(32, B_), 256, 0, stream>>>(x, xsT);
  k2_qkv<<<dim3(48, B_), 256, 0, stream>>>(xsT, wqkv_h, wqkv_l,
                                           q_scale, q_bias, k_scale, k_bias,
                                           v_scale, v_bias, q_s8, k_s8, v_s8);
  k3_attn<<<dim3(4, NH_, B_), 256, 0, stream>>>(q_s8, k_s8, v_s8, a_s8);
  k0_split<<<512, 256, 0, stream>>>(wp, wp_h, wp_l, 131072);   // q_s8 dead now
  k4_pconv<<<dim3(8, T_ * B_), 256, 0, stream>>>(a_s8, wp_h, wp_l,
                                                 p_scale, p_bias, (float*)d_out);
}